// Round 1
// 623.597 us; speedup vs baseline: 1.0506x; 1.0506x over previous
//
#include <hip/hip_runtime.h>
#include <stdint.h>

typedef unsigned short u16;
typedef short short8 __attribute__((ext_vector_type(8)));
typedef float floatx4 __attribute__((ext_vector_type(4)));

__device__ __forceinline__ u16 f2bf(float f) {
  union { float f; unsigned u; } t; t.f = f;
  return (u16)((t.u + 0x7fffu + ((t.u >> 16) & 1u)) >> 16);
}
__device__ __forceinline__ float lo16(unsigned w) { union { unsigned u; float f; } t; t.u = w << 16; return t.f; }
__device__ __forceinline__ float hi16(unsigned w) { union { unsigned u; float f; } t; t.u = w & 0xffff0000u; return t.f; }
__device__ __forceinline__ void unpack8(uint4 v, float* f) {
  f[0]=lo16(v.x); f[1]=hi16(v.x); f[2]=lo16(v.y); f[3]=hi16(v.y);
  f[4]=lo16(v.z); f[5]=hi16(v.z); f[6]=lo16(v.w); f[7]=hi16(v.w);
}
__device__ __forceinline__ uint4 pack8(const u16* o) {
  uint4 v;
  v.x = (unsigned)o[0] | ((unsigned)o[1] << 16);
  v.y = (unsigned)o[2] | ((unsigned)o[3] << 16);
  v.z = (unsigned)o[4] | ((unsigned)o[5] << 16);
  v.w = (unsigned)o[6] | ((unsigned)o[7] << 16);
  return v;
}

// async global->LDS, 16B per lane; lds dst is wave-uniform base + lane*16
__device__ __forceinline__ void gll16(const void* g, void* l) {
  __builtin_amdgcn_global_load_lds(
      (const __attribute__((address_space(1))) void*)(uintptr_t)(g),
      (__attribute__((address_space(3))) void*)(unsigned)(uintptr_t)(l),
      16, 0, 0);
}

// ---------------------------------------------------------------------------
// prep_convert: one launch for all weight conversions.
// ---------------------------------------------------------------------------
__device__ __forceinline__ void cvt4(const float* s, u16* d, int g) {
  float4 v = *(const float4*)(s + (size_t)g * 4);
  ushort4 o; o.x = f2bf(v.x); o.y = f2bf(v.y); o.z = f2bf(v.z); o.w = f2bf(v.w);
  *(ushort4*)(d + (size_t)g * 4) = o;
}
__global__ __launch_bounds__(256)
void prep_convert(const float* __restrict__ inw, const float* __restrict__ phw,
                  const float* __restrict__ imw, const float* __restrict__ ow,
                  const float* __restrict__ outw,
                  u16* __restrict__ inw_bf, u16* __restrict__ phw_bf,
                  u16* __restrict__ imw_bf, u16* __restrict__ ow_bf,
                  u16* __restrict__ outwT) {
  int which = blockIdx.y;
  int g = blockIdx.x * 256 + threadIdx.x;
  if (which == 0) { if (g < 196608) cvt4(inw, inw_bf, g); }
  else if (which == 1) { if (g < 65536) cvt4(phw, phw_bf, g); }
  else if (which == 2) { if (g < 65536) cvt4(imw, imw_bf, g); }
  else if (which == 3) { if (g < 131072) cvt4(ow, ow_bf, g); }
  else {
    if (g < 65536) {
      int i0 = (g >> 9) * 4, j = g & 511;
      ushort4 o;
      o.x = f2bf(outw[(size_t)(i0 + 0) * 512 + j]);
      o.y = f2bf(outw[(size_t)(i0 + 1) * 512 + j]);
      o.z = f2bf(outw[(size_t)(i0 + 2) * 512 + j]);
      o.w = f2bf(outw[(size_t)(i0 + 3) * 512 + j]);
      outwT[(size_t)j * 512 + i0 + 0] = o.x;
      outwT[(size_t)j * 512 + i0 + 1] = o.y;
      outwT[(size_t)j * 512 + i0 + 2] = o.z;
      outwT[(size_t)j * 512 + i0 + 3] = o.w;
    }
  }
}

__global__ __launch_bounds__(256)
void uv_kernel(const float* __restrict__ phw, const float* __restrict__ phb,
               const float* __restrict__ imw, const float* __restrict__ imb,
               const float* __restrict__ outb, float* __restrict__ uv) {
  int g = blockIdx.x * 256 + threadIdx.x;  // 0..1023
  int i = g & 511;
  const float* W = (g < 512) ? phw : imw;
  const float* bb = (g < 512) ? phb : imb;
  float s = bb[i];
#pragma unroll 4
  for (int c = 0; c < 512; ++c) s += W[(size_t)i * 512 + c] * outb[c];
  uv[g] = s;
}

__global__ __launch_bounds__(256)
void bcomb_kernel(const float* __restrict__ ow, const float* __restrict__ ob,
                  const float* __restrict__ uv, float* __restrict__ bcomb) {
  int i = blockIdx.x * 256 + threadIdx.x;  // 0..511
  float s = ob[i];
#pragma unroll 4
  for (int r = 0; r < 1024; ++r) s += ow[(size_t)i * 1024 + r] * uv[r];
  bcomb[i] = s;
}

// ---------------------------------------------------------------------------
// build_xe: xe[(b*2048+t)*2+d][c] = bf16( x[b][c][d][t] + emb[d][c] )
// ---------------------------------------------------------------------------
__global__ __launch_bounds__(256)
void build_xe(const float* __restrict__ x, const float* __restrict__ emb,
              u16* __restrict__ xe) {
  __shared__ u16 tile[64][66];
  int bt = blockIdx.x;
  int tt = bt & 31, ct = (bt >> 5) & 7, d = (bt >> 8) & 1, b = bt >> 9;
  int t0 = tt * 64, c0 = ct * 64;
  int tid = threadIdx.x;
  int q = tid & 15, r = tid >> 4;
#pragma unroll
  for (int p = 0; p < 4; ++p) {
    int c = p * 16 + r;
    const float* src = x + ((size_t)((b * 512 + c0 + c) * 2 + d)) * 2048 + t0 + q * 4;
    float4 v = *(const float4*)src;
    float e = emb[d * 512 + c0 + c];
    ushort4 o; o.x = f2bf(v.x + e); o.y = f2bf(v.y + e); o.z = f2bf(v.z + e); o.w = f2bf(v.w + e);
    *(ushort4*)&tile[c][q * 4] = o;
  }
  __syncthreads();
  int cq = tid & 7, tp = tid >> 3;
  int cc0 = cq * 8;
  u16 o0[8], o1[8];
#pragma unroll
  for (int i = 0; i < 8; ++i) {
    unsigned w2 = *(const unsigned*)&tile[cc0 + i][2 * tp];
    o0[i] = (u16)(w2 & 0xffffu); o1[i] = (u16)(w2 >> 16);
  }
  size_t n = (size_t)b * 2048 + t0 + 2 * tp;
  *(uint4*)(xe + (n * 2 + d) * 512 + c0 + cc0) = pack8(o0);
  *(uint4*)(xe + ((n + 1) * 2 + d) * 512 + c0 + cc0) = pack8(o1);
}

// ---------------------------------------------------------------------------
// gemm_bt (legacy 128x128, kept for the tiny 512^3 weight-fold GEMMs)
// ---------------------------------------------------------------------------
template<int EPI>
__global__ __launch_bounds__(256, 3)
void gemm_bt(const u16* __restrict__ A, int lda,
             const u16* __restrict__ B, int ldb,
             const float* __restrict__ bias,
             void* __restrict__ Cv, int ldc, int K,
             const float* __restrict__ P) {
  __shared__ u16 As[128 * 64];
  __shared__ u16 Bs[128 * 64];
  int m0 = blockIdx.x * 128;
  int n0 = blockIdx.y * 128;
  int t = threadIdx.x;
  int lane = t & 63;
  int w = t >> 6;
  int wm = (w >> 1) * 64, wn = (w & 1) * 64;
  int l15 = lane & 15, quad = lane >> 4;

  floatx4 acc[4][4];
#pragma unroll
  for (int i = 0; i < 4; ++i)
#pragma unroll
    for (int j = 0; j < 4; ++j) acc[i][j] = (floatx4){0.f, 0.f, 0.f, 0.f};

  int lrow = lane >> 3, lcol = (lane & 7) * 8;
  const u16* gA = A + (size_t)(m0 + w * 32 + lrow) * lda + lcol;
  const u16* gB = B + (size_t)(n0 + w * 32 + lrow) * ldb + lcol;
  u16* lA = As + (w * 32) * 64;
  u16* lB = Bs + (w * 32) * 64;

  int KT = K >> 6;
  for (int kt = 0; kt < KT; ++kt) {
    int ko = kt * 64;
#pragma unroll
    for (int j = 0; j < 4; ++j) {
      gll16(gA + (size_t)(j * 8) * lda + ko, lA + (j * 8) * 64);
      gll16(gB + (size_t)(j * 8) * ldb + ko, lB + (j * 8) * 64);
    }
    __syncthreads();
#pragma unroll
    for (int ki = 0; ki < 2; ++ki) {
      short8 af[4], bfv[4];
#pragma unroll
      for (int i = 0; i < 4; ++i)
        af[i] = *(const short8*)&As[(wm + i * 16 + l15) * 64 + ki * 32 + quad * 8];
#pragma unroll
      for (int j = 0; j < 4; ++j)
        bfv[j] = *(const short8*)&Bs[(wn + j * 16 + l15) * 64 + ki * 32 + quad * 8];
#pragma unroll
      for (int i = 0; i < 4; ++i)
#pragma unroll
        for (int j = 0; j < 4; ++j)
          acc[i][j] = __builtin_amdgcn_mfma_f32_16x16x32_bf16(af[i], bfv[j], acc[i][j], 0, 0, 0);
    }
    __syncthreads();
  }

#pragma unroll
  for (int i = 0; i < 4; ++i) {
    int mrow = m0 + wm + i * 16 + quad * 4;
    float4 P0, P1;
    if (EPI == 2) {
      int np0 = mrow >> 1;
      P0 = *(const float4*)&P[((size_t)np0 * 4 + blockIdx.y) * 4];
      P1 = *(const float4*)&P[((size_t)(np0 + 1) * 4 + blockIdx.y) * 4];
    }
#pragma unroll
    for (int j = 0; j < 4; ++j) {
      int col = n0 + wn + j * 16 + l15;
      float bv = bias[col];
      floatx4 a = acc[i][j];
      if (EPI == 1) {
        int bb = mrow >> 11, ti = mrow & 2047;
        float4 o; o.x = a[0] + bv; o.y = a[1] + bv; o.z = a[2] + bv; o.w = a[3] + bv;
        *(float4*)&((float*)Cv)[((size_t)bb * ldc + col) * 2048 + ti] = o;
      } else if (EPI == 2) {
        float a0 = a[0] + bv, a1 = a[1] + bv, a2 = a[2] + bv, a3 = a[3] + bv;
        u16* C = (u16*)Cv;
        C[(size_t)(mrow + 0) * ldc + col] = f2bf(P0.x * a0 + P0.y * a1);
        C[(size_t)(mrow + 1) * ldc + col] = f2bf(P0.z * a0 + P0.w * a1);
        C[(size_t)(mrow + 2) * ldc + col] = f2bf(P1.x * a2 + P1.y * a3);
        C[(size_t)(mrow + 3) * ldc + col] = f2bf(P1.z * a2 + P1.w * a3);
      } else {
        u16* C = (u16*)Cv;
#pragma unroll
        for (int r = 0; r < 4; ++r)
          C[(size_t)(mrow + r) * ldc + col] = f2bf(a[r] + bv);
      }
    }
  }
}

// ---------------------------------------------------------------------------
// gemm256: 256x256 tile, 8 waves (2M x 4N), BK=32, 4-deep LDS ring buffer,
// counted vmcnt pipeline (T3+T4), setprio around MFMA cluster (T5),
// chunked XCD block swizzle (T1). BK=32 rows are 64 B so fragment
// ds_read_b128 is bank-conflict-free without swizzle (row parity alternates
// bank halves). LDS ring: 4 x (A 16 KiB + B 16 KiB) = 128 KiB.
// Schedule per phase t: stage tile t+3 (4 x global_load_lds dwordx4/thread),
// s_waitcnt vmcnt(12)  [tiles t+1..t+3 stay in flight; never 0 in main loop],
// s_barrier, 12 x ds_read_b128, 32 x MFMA, s_barrier.
// ---------------------------------------------------------------------------
__device__ __forceinline__ void compute_tile(const u16 (&Asr)[4][8192],
                                             const u16 (&Bsr)[4][8192],
                                             int bo, int aoff, int boff,
                                             floatx4 (&acc)[8][4]) {
  short8 af[8], bfv[4];
#pragma unroll
  for (int i = 0; i < 8; ++i)
    af[i] = *(const short8*)&Asr[bo][aoff + i * 512];
#pragma unroll
  for (int j = 0; j < 4; ++j)
    bfv[j] = *(const short8*)&Bsr[bo][boff + j * 512];
  __builtin_amdgcn_s_setprio(1);
#pragma unroll
  for (int i = 0; i < 8; ++i)
#pragma unroll
    for (int j = 0; j < 4; ++j)
      acc[i][j] = __builtin_amdgcn_mfma_f32_16x16x32_bf16(af[i], bfv[j], acc[i][j], 0, 0, 0);
  __builtin_amdgcn_s_setprio(0);
}

template<int EPI>
__global__ __launch_bounds__(512, 2)
void gemm256(const u16* __restrict__ A, int lda,
             const u16* __restrict__ B, int ldb,
             const float* __restrict__ bias,
             void* __restrict__ Cv, int ldc, int K,
             const float* __restrict__ P, int nbs) {
  __shared__ u16 As[4][8192];
  __shared__ u16 Bs[4][8192];
  // chunked XCD swizzle: XCD x gets a contiguous g-range; same-m n-blocks
  // run concurrently on one XCD -> A-stripe L2 reuse. grid % 8 == 0 always.
  int nwg = gridDim.x;
  int bid = blockIdx.x;
  int chunk = nwg >> 3;
  int g = (bid & 7) * chunk + (bid >> 3);
  int nb = g & ((1 << nbs) - 1), mb = g >> nbs;
  int m0 = mb * 256, n0 = nb * 256;
  int t = threadIdx.x;
  int lane = t & 63, w = t >> 6;
  int wr = w >> 2, wc = w & 3;
  int l15 = lane & 15, quad = lane >> 4;
  int wb = w * 512;                 // wave-uniform LDS staging base (elems)
  int srow = t >> 2, sch = (t & 3) * 8;
  const u16* gA0 = A + (size_t)(m0 + srow) * lda + sch;
  const u16* gA1 = gA0 + (size_t)128 * lda;
  const u16* gB0 = B + (size_t)(n0 + srow) * ldb + sch;
  const u16* gB1 = gB0 + (size_t)128 * ldb;

  floatx4 acc[8][4];
#pragma unroll
  for (int i = 0; i < 8; ++i)
#pragma unroll
    for (int j = 0; j < 4; ++j) acc[i][j] = (floatx4){0.f, 0.f, 0.f, 0.f};

  int aoff = (wr * 128 + l15) * 32 + quad * 8;
  int boff = (wc * 64 + l15) * 32 + quad * 8;
  int KT = K >> 5;

#define STAGE256(ts) { int _b = (ts) & 3; int _ko = (ts) * 32;             \
    gll16(gA0 + _ko, (void*)&As[_b][wb]);                                  \
    gll16(gA1 + _ko, (void*)&As[_b][wb + 4096]);                           \
    gll16(gB0 + _ko, (void*)&Bs[_b][wb]);                                  \
    gll16(gB1 + _ko, (void*)&Bs[_b][wb + 4096]); }

  STAGE256(0)
  STAGE256(1)
  STAGE256(2)
  for (int tt = 0; tt < KT - 3; ++tt) {
    STAGE256(tt + 3)
    asm volatile("s_waitcnt vmcnt(12)" ::: "memory");
    asm volatile("s_barrier" ::: "memory");
    compute_tile(As, Bs, tt & 3, aoff, boff, acc);
    asm volatile("s_barrier" ::: "memory");
  }
  asm volatile("s_waitcnt vmcnt(8)" ::: "memory");
  asm volatile("s_barrier" ::: "memory");
  compute_tile(As, Bs, (KT - 3) & 3, aoff, boff, acc);
  asm volatile("s_waitcnt vmcnt(4)" ::: "memory");
  asm volatile("s_barrier" ::: "memory");
  compute_tile(As, Bs, (KT - 2) & 3, aoff, boff, acc);
  asm volatile("s_waitcnt vmcnt(0)" ::: "memory");
  asm volatile("s_barrier" ::: "memory");
  compute_tile(As, Bs, (KT - 1) & 3, aoff, boff, acc);
#undef STAGE256

  // epilogue: C/D layout col = lane&15, row = quad*4 + reg  [m89-verified]
#pragma unroll
  for (int i = 0; i < 8; ++i) {
    int mrow = m0 + wr * 128 + i * 16 + quad * 4;
#pragma unroll
    for (int j = 0; j < 4; ++j) {
      int col = n0 + wc * 64 + j * 16 + l15;
      float bv = bias[col];
      floatx4 a = acc[i][j];
      if (EPI == 1) {
        int bb = mrow >> 11, ti = mrow & 2047;
        float4 o; o.x = a[0] + bv; o.y = a[1] + bv; o.z = a[2] + bv; o.w = a[3] + bv;
        *(float4*)&((float*)Cv)[((size_t)bb * ldc + col) * 2048 + ti] = o;
      } else if (EPI == 2) {
        int np0 = mrow >> 1;
        int h = col >> 7;   // head from output column (128-wide head slices)
        float4 P0 = *(const float4*)&P[((size_t)np0 * 4 + h) * 4];
        float4 P1 = *(const float4*)&P[((size_t)(np0 + 1) * 4 + h) * 4];
        float a0 = a[0] + bv, a1 = a[1] + bv, a2 = a[2] + bv, a3 = a[3] + bv;
        u16* C = (u16*)Cv;
        C[(size_t)(mrow + 0) * ldc + col] = f2bf(P0.x * a0 + P0.y * a1);
        C[(size_t)(mrow + 1) * ldc + col] = f2bf(P0.z * a0 + P0.w * a1);
        C[(size_t)(mrow + 2) * ldc + col] = f2bf(P1.x * a2 + P1.y * a3);
        C[(size_t)(mrow + 3) * ldc + col] = f2bf(P1.z * a2 + P1.w * a3);
      } else {
        u16* C = (u16*)Cv;
#pragma unroll
        for (int r = 0; r < 4; ++r)
          C[(size_t)(mrow + r) * ldc + col] = f2bf(a[r] + bv);
      }
    }
  }
}

// ---------------------------------------------------------------------------
// score_kernel: thread per (n,h); QK row 2n/2n+1, q at col h*128, k at 512+h*128.
// ---------------------------------------------------------------------------
__global__ __launch_bounds__(256)
void score_kernel(const u16* __restrict__ QK, float* __restrict__ P,
                  float* __restrict__ asum) {
  int g = blockIdx.x * 256 + threadIdx.x;
  int n = g >> 2, h = g & 3;
  const u16* q0 = QK + (size_t)(2 * n) * 1024 + h * 128;
  const u16* q1 = q0 + 1024;
  const u16* k0 = q0 + 512;
  const u16* k1 = k0 + 1024;

  float s00 = 0.f, s01 = 0.f, s10 = 0.f, s11 = 0.f;
#pragma unroll
  for (int c = 0; c < 128; c += 8) {
    float fq0[8], fq1[8], fk0[8], fk1[8];
    unpack8(*(const uint4*)(q0 + c), fq0);
    unpack8(*(const uint4*)(q1 + c), fq1);
    unpack8(*(const uint4*)(k0 + c), fk0);
    unpack8(*(const uint4*)(k1 + c), fk1);
#pragma unroll
    for (int u = 0; u < 8; ++u) {
      s00 += fq0[u] * fk0[u]; s01 += fq0[u] * fk1[u];
      s10 += fq1[u] * fk0[u]; s11 += fq1[u] * fk1[u];
    }
  }
  const float sc = 0.08838834764831845f;  // 1/sqrt(128)
  s00 *= sc; s01 *= sc; s10 *= sc; s11 *= sc;
  float m0v = fmaxf(s00, s01), m1v = fmaxf(s10, s11);
  float e00 = __expf(s00 - m0v), e01 = __expf(s01 - m0v);
  float e10 = __expf(s10 - m1v), e11 = __expf(s11 - m1v);
  float i0 = 1.f / (e00 + e01), i1 = 1.f / (e10 + e11);
  float4 p; p.x = e00 * i0; p.y = e01 * i0; p.z = e10 * i1; p.w = e11 * i1;
  *(float4*)&P[(size_t)g * 4] = p;

  float pv[4] = {p.x, p.y, p.z, p.w};
#pragma unroll
  for (int k2 = 0; k2 < 4; ++k2) {
    float v = pv[k2];
    v += __shfl_down(v, 32, 64); v += __shfl_down(v, 16, 64);
    v += __shfl_down(v, 8, 64);  v += __shfl_down(v, 4, 64);
    v += __shfl_down(v, 2, 64);  v += __shfl_down(v, 1, 64);
    pv[k2] = v;
  }
  __shared__ float red[4][4];
  int lane = threadIdx.x & 63, wv = threadIdx.x >> 6;
  if (lane == 0) { red[wv][0] = pv[0]; red[wv][1] = pv[1]; red[wv][2] = pv[2]; red[wv][3] = pv[3]; }
  __syncthreads();
  if (threadIdx.x < 4) {
    float s = red[0][threadIdx.x] + red[1][threadIdx.x] + red[2][threadIdx.x] + red[3][threadIdx.x];
    int b = (blockIdx.x * 64) >> 11;
    atomicAdd(&asum[b * 4 + threadIdx.x], s);
  }
}

__global__ void avg_kernel(const float* __restrict__ asum, float* __restrict__ out) {
  int i = threadIdx.x;  // 64 = 16 b * 4
  out[16777216 + i] = asum[i] * (1.0f / 8192.0f);  // / (H=4 * T=2048)
}

// ---------------------------------------------------------------------------
// Workspace layout unchanged (~206 MiB). xe staged in d_out.
// ---------------------------------------------------------------------------
extern "C" void kernel_launch(void* const* d_in, const int* in_sizes, int n_in,
                              void* d_out, int out_size, void* d_ws, size_t ws_size,
                              hipStream_t stream) {
  const float* x    = (const float*)d_in[0];
  const float* emb  = (const float*)d_in[1];
  const float* inw  = (const float*)d_in[2];
  const float* inb  = (const float*)d_in[3];
  const float* outw = (const float*)d_in[4];
  const float* outb = (const float*)d_in[5];
  const float* phw  = (const float*)d_in[6];
  const float* phb  = (const float*)d_in[7];
  const float* imw  = (const float*)d_in[8];
  const float* imb  = (const float*)d_in[9];
  const float* ow   = (const float*)d_in[10];
  const float* ob   = (const float*)d_in[11];
  float* outF = (float*)d_out;

  char* wsb = (char*)d_ws;
  u16*   ctx    = (u16*)wsb;
  u16*   QK     = (u16*)(wsb + 67108864);
  u16*   outwT  = (u16*)(wsb + 67108864);
  u16*   phw_bf = (u16*)(wsb + 67633152);
  u16*   imw_bf = (u16*)(wsb + 68157440);
  u16*   ow_bf  = (u16*)(wsb + 68681728);
  u16*   T1T    = (u16*)(wsb + 69730304);
  u16*   T2T    = (u16*)(wsb + 70254592);
  u16*   inw_bf = (u16*)(wsb + 201326592);
  u16*   Wcomb  = (u16*)(wsb + 202899456);
  float* uv     = (float*)(wsb + 203948032);
  float* bcomb  = (float*)(wsb + 203952128);
  float* P      = (float*)(wsb + 203954176);
  float* asum   = (float*)(wsb + 206051328);
  float* zbias  = (float*)(wsb + 206051584);
  u16*   xe     = (u16*)d_out;

  // zero asum (256 B) + zbias (2 KiB) in one memset
  hipMemsetAsync(asum, 0, 2304, stream);

  // xe = transpose(x) + emb  (bf16, staged in d_out) -- biggest prep, first
  build_xe<<<8192, 256, 0, stream>>>(x, emb, xe);

  // weight conversions (one launch), then MFMA weight-fold chain
  prep_convert<<<dim3(768, 5), 256, 0, stream>>>(inw, phw, imw, ow, outw,
                                                 inw_bf, phw_bf, imw_bf, ow_bf, outwT);
  // T1T = outwT @ phw^T ; T2T = outwT @ imw^T   (512x512x512, legacy kernel)
  gemm_bt<0><<<dim3(4, 4), 256, 0, stream>>>(outwT, 512, phw_bf, 512, zbias, T1T, 512, 512, nullptr);
  gemm_bt<0><<<dim3(4, 4), 256, 0, stream>>>(outwT, 512, imw_bf, 512, zbias, T2T, 512, 512, nullptr);
  // Wcomb[:, :512] = ow_L @ T1 ; Wcomb[:, 512:] = ow_R @ T2
  gemm_bt<0><<<dim3(4, 4), 256, 0, stream>>>(ow_bf, 1024, T1T, 512, zbias, Wcomb, 1024, 512, nullptr);
  gemm_bt<0><<<dim3(4, 4), 256, 0, stream>>>(ow_bf + 512, 1024, T2T, 512, zbias, Wcomb + 512, 1024, 512, nullptr);
  // combined bias (fp32 path, tiny)
  uv_kernel<<<4, 256, 0, stream>>>(phw, phb, imw, imb, outb, uv);
  bcomb_kernel<<<2, 256, 0, stream>>>(ow, ob, uv, bcomb);

  // QK = xe @ [Wq;Wk]^T + [bq;bk]   (65536 x 1024 x 512)  -- 256^2 pipelined
  gemm256<0><<<1024, 512, 0, stream>>>(xe, 512, inw_bf, 512, inb,
                                       QK, 1024, 512, nullptr, 2);
  // 2x2 softmax -> P, asum
  score_kernel<<<512, 256, 0, stream>>>(QK, P, asum);
  // V GEMM + P-mix epilogue -> ctx   (65536 x 512 x 512)
  gemm256<2><<<512, 512, 0, stream>>>(xe, 512, inw_bf + 524288, 512,
                                      inb + 1024, ctx, 512, 512, P, 1);
  // folded tail: out = ctx(pairs, K=1024) @ Wcomb^T + bcomb, transposed (B,C,T)
  gemm256<1><<<256, 512, 0, stream>>>(ctx, 1024, Wcomb, 1024,
                                      bcomb, outF, 512, 1024, nullptr, 1);
  avg_kernel<<<1, 64, 0, stream>>>(asum, outF);
}

// Round 2
// 618.517 us; speedup vs baseline: 1.0593x; 1.0082x over previous
//
#include <hip/hip_runtime.h>
#include <stdint.h>

typedef unsigned short u16;
typedef short short8 __attribute__((ext_vector_type(8)));
typedef float floatx4 __attribute__((ext_vector_type(4)));

__device__ __forceinline__ u16 f2bf(float f) {
  union { float f; unsigned u; } t; t.f = f;
  return (u16)((t.u + 0x7fffu + ((t.u >> 16) & 1u)) >> 16);
}
__device__ __forceinline__ float lo16(unsigned w) { union { unsigned u; float f; } t; t.u = w << 16; return t.f; }
__device__ __forceinline__ float hi16(unsigned w) { union { unsigned u; float f; } t; t.u = w & 0xffff0000u; return t.f; }
__device__ __forceinline__ void unpack8(uint4 v, float* f) {
  f[0]=lo16(v.x); f[1]=hi16(v.x); f[2]=lo16(v.y); f[3]=hi16(v.y);
  f[4]=lo16(v.z); f[5]=hi16(v.z); f[6]=lo16(v.w); f[7]=hi16(v.w);
}
__device__ __forceinline__ uint4 pack8(const u16* o) {
  uint4 v;
  v.x = (unsigned)o[0] | ((unsigned)o[1] << 16);
  v.y = (unsigned)o[2] | ((unsigned)o[3] << 16);
  v.z = (unsigned)o[4] | ((unsigned)o[5] << 16);
  v.w = (unsigned)o[6] | ((unsigned)o[7] << 16);
  return v;
}

// async global->LDS, 16B per lane; lds dst is wave-uniform base + lane*16
__device__ __forceinline__ void gll16(const void* g, void* l) {
  __builtin_amdgcn_global_load_lds(
      (const __attribute__((address_space(1))) void*)(uintptr_t)(g),
      (__attribute__((address_space(3))) void*)(unsigned)(uintptr_t)(l),
      16, 0, 0);
}

// ---------------------------------------------------------------------------
// prep_convert: one launch for all weight conversions.
// ---------------------------------------------------------------------------
__device__ __forceinline__ void cvt4(const float* s, u16* d, int g) {
  float4 v = *(const float4*)(s + (size_t)g * 4);
  ushort4 o; o.x = f2bf(v.x); o.y = f2bf(v.y); o.z = f2bf(v.z); o.w = f2bf(v.w);
  *(ushort4*)(d + (size_t)g * 4) = o;
}
__global__ __launch_bounds__(256)
void prep_convert(const float* __restrict__ inw, const float* __restrict__ phw,
                  const float* __restrict__ imw, const float* __restrict__ ow,
                  const float* __restrict__ outw,
                  u16* __restrict__ inw_bf, u16* __restrict__ phw_bf,
                  u16* __restrict__ imw_bf, u16* __restrict__ ow_bf,
                  u16* __restrict__ outwT) {
  int which = blockIdx.y;
  int g = blockIdx.x * 256 + threadIdx.x;
  if (which == 0) { if (g < 196608) cvt4(inw, inw_bf, g); }
  else if (which == 1) { if (g < 65536) cvt4(phw, phw_bf, g); }
  else if (which == 2) { if (g < 65536) cvt4(imw, imw_bf, g); }
  else if (which == 3) { if (g < 131072) cvt4(ow, ow_bf, g); }
  else {
    if (g < 65536) {
      int i0 = (g >> 9) * 4, j = g & 511;
      ushort4 o;
      o.x = f2bf(outw[(size_t)(i0 + 0) * 512 + j]);
      o.y = f2bf(outw[(size_t)(i0 + 1) * 512 + j]);
      o.z = f2bf(outw[(size_t)(i0 + 2) * 512 + j]);
      o.w = f2bf(outw[(size_t)(i0 + 3) * 512 + j]);
      outwT[(size_t)j * 512 + i0 + 0] = o.x;
      outwT[(size_t)j * 512 + i0 + 1] = o.y;
      outwT[(size_t)j * 512 + i0 + 2] = o.z;
      outwT[(size_t)j * 512 + i0 + 3] = o.w;
    }
  }
}

__global__ __launch_bounds__(256)
void uv_kernel(const float* __restrict__ phw, const float* __restrict__ phb,
               const float* __restrict__ imw, const float* __restrict__ imb,
               const float* __restrict__ outb, float* __restrict__ uv) {
  int g = blockIdx.x * 256 + threadIdx.x;  // 0..1023
  int i = g & 511;
  const float* W = (g < 512) ? phw : imw;
  const float* bb = (g < 512) ? phb : imb;
  float s = bb[i];
#pragma unroll 4
  for (int c = 0; c < 512; ++c) s += W[(size_t)i * 512 + c] * outb[c];
  uv[g] = s;
}

__global__ __launch_bounds__(256)
void bcomb_kernel(const float* __restrict__ ow, const float* __restrict__ ob,
                  const float* __restrict__ uv, float* __restrict__ bcomb) {
  int i = blockIdx.x * 256 + threadIdx.x;  // 0..511
  float s = ob[i];
#pragma unroll 4
  for (int r = 0; r < 1024; ++r) s += ow[(size_t)i * 1024 + r] * uv[r];
  bcomb[i] = s;
}

// ---------------------------------------------------------------------------
// build_xe: xe[(b*2048+t)*2+d][c] = bf16( x[b][c][d][t] + emb[d][c] )
// ---------------------------------------------------------------------------
__global__ __launch_bounds__(256)
void build_xe(const float* __restrict__ x, const float* __restrict__ emb,
              u16* __restrict__ xe) {
  __shared__ u16 tile[64][66];
  int bt = blockIdx.x;
  int tt = bt & 31, ct = (bt >> 5) & 7, d = (bt >> 8) & 1, b = bt >> 9;
  int t0 = tt * 64, c0 = ct * 64;
  int tid = threadIdx.x;
  int q = tid & 15, r = tid >> 4;
#pragma unroll
  for (int p = 0; p < 4; ++p) {
    int c = p * 16 + r;
    const float* src = x + ((size_t)((b * 512 + c0 + c) * 2 + d)) * 2048 + t0 + q * 4;
    float4 v = *(const float4*)src;
    float e = emb[d * 512 + c0 + c];
    ushort4 o; o.x = f2bf(v.x + e); o.y = f2bf(v.y + e); o.z = f2bf(v.z + e); o.w = f2bf(v.w + e);
    *(ushort4*)&tile[c][q * 4] = o;
  }
  __syncthreads();
  int cq = tid & 7, tp = tid >> 3;
  int cc0 = cq * 8;
  u16 o0[8], o1[8];
#pragma unroll
  for (int i = 0; i < 8; ++i) {
    unsigned w2 = *(const unsigned*)&tile[cc0 + i][2 * tp];
    o0[i] = (u16)(w2 & 0xffffu); o1[i] = (u16)(w2 >> 16);
  }
  size_t n = (size_t)b * 2048 + t0 + 2 * tp;
  *(uint4*)(xe + (n * 2 + d) * 512 + c0 + cc0) = pack8(o0);
  *(uint4*)(xe + ((n + 1) * 2 + d) * 512 + c0 + cc0) = pack8(o1);
}

// ---------------------------------------------------------------------------
// gemm_bt (legacy 128x128, kept for the tiny 512^3 weight-fold GEMMs)
// ---------------------------------------------------------------------------
template<int EPI>
__global__ __launch_bounds__(256, 3)
void gemm_bt(const u16* __restrict__ A, int lda,
             const u16* __restrict__ B, int ldb,
             const float* __restrict__ bias,
             void* __restrict__ Cv, int ldc, int K,
             const float* __restrict__ P) {
  __shared__ u16 As[128 * 64];
  __shared__ u16 Bs[128 * 64];
  int m0 = blockIdx.x * 128;
  int n0 = blockIdx.y * 128;
  int t = threadIdx.x;
  int lane = t & 63;
  int w = t >> 6;
  int wm = (w >> 1) * 64, wn = (w & 1) * 64;
  int l15 = lane & 15, quad = lane >> 4;

  floatx4 acc[4][4];
#pragma unroll
  for (int i = 0; i < 4; ++i)
#pragma unroll
    for (int j = 0; j < 4; ++j) acc[i][j] = (floatx4){0.f, 0.f, 0.f, 0.f};

  int lrow = lane >> 3, lcol = (lane & 7) * 8;
  const u16* gA = A + (size_t)(m0 + w * 32 + lrow) * lda + lcol;
  const u16* gB = B + (size_t)(n0 + w * 32 + lrow) * ldb + lcol;
  u16* lA = As + (w * 32) * 64;
  u16* lB = Bs + (w * 32) * 64;

  int KT = K >> 6;
  for (int kt = 0; kt < KT; ++kt) {
    int ko = kt * 64;
#pragma unroll
    for (int j = 0; j < 4; ++j) {
      gll16(gA + (size_t)(j * 8) * lda + ko, lA + (j * 8) * 64);
      gll16(gB + (size_t)(j * 8) * ldb + ko, lB + (j * 8) * 64);
    }
    __syncthreads();
#pragma unroll
    for (int ki = 0; ki < 2; ++ki) {
      short8 af[4], bfv[4];
#pragma unroll
      for (int i = 0; i < 4; ++i)
        af[i] = *(const short8*)&As[(wm + i * 16 + l15) * 64 + ki * 32 + quad * 8];
#pragma unroll
      for (int j = 0; j < 4; ++j)
        bfv[j] = *(const short8*)&Bs[(wn + j * 16 + l15) * 64 + ki * 32 + quad * 8];
#pragma unroll
      for (int i = 0; i < 4; ++i)
#pragma unroll
        for (int j = 0; j < 4; ++j)
          acc[i][j] = __builtin_amdgcn_mfma_f32_16x16x32_bf16(af[i], bfv[j], acc[i][j], 0, 0, 0);
    }
    __syncthreads();
  }

#pragma unroll
  for (int i = 0; i < 4; ++i) {
    int mrow = m0 + wm + i * 16 + quad * 4;
    float4 P0, P1;
    if (EPI == 2) {
      int np0 = mrow >> 1;
      P0 = *(const float4*)&P[((size_t)np0 * 4 + blockIdx.y) * 4];
      P1 = *(const float4*)&P[((size_t)(np0 + 1) * 4 + blockIdx.y) * 4];
    }
#pragma unroll
    for (int j = 0; j < 4; ++j) {
      int col = n0 + wn + j * 16 + l15;
      float bv = bias[col];
      floatx4 a = acc[i][j];
      if (EPI == 1) {
        int bb = mrow >> 11, ti = mrow & 2047;
        float4 o; o.x = a[0] + bv; o.y = a[1] + bv; o.z = a[2] + bv; o.w = a[3] + bv;
        *(float4*)&((float*)Cv)[((size_t)bb * ldc + col) * 2048 + ti] = o;
      } else if (EPI == 2) {
        float a0 = a[0] + bv, a1 = a[1] + bv, a2 = a[2] + bv, a3 = a[3] + bv;
        u16* C = (u16*)Cv;
        C[(size_t)(mrow + 0) * ldc + col] = f2bf(P0.x * a0 + P0.y * a1);
        C[(size_t)(mrow + 1) * ldc + col] = f2bf(P0.z * a0 + P0.w * a1);
        C[(size_t)(mrow + 2) * ldc + col] = f2bf(P1.x * a2 + P1.y * a3);
        C[(size_t)(mrow + 3) * ldc + col] = f2bf(P1.z * a2 + P1.w * a3);
      } else {
        u16* C = (u16*)Cv;
#pragma unroll
        for (int r = 0; r < 4; ++r)
          C[(size_t)(mrow + r) * ldc + col] = f2bf(a[r] + bv);
      }
    }
  }
}

// ---------------------------------------------------------------------------
// gemm256: 256x256 tile, 8 waves (2M x 4N), BK=32, 4-deep LDS ring buffer.
// T3 fine phase interleave (m201 pattern): each K-tile = 2 phases of
//   { issue ds_read_b128 subtile + issue half-tile global_load_lds ->
//     s_barrier -> lgkmcnt(0) -> sched_barrier -> setprio(1) 16 MFMA
//     setprio(0) -> s_barrier }
// T4 counted vmcnt: vmcnt(8) after phase-1 MFMAs (3 tiles in flight, never 0
// in main loop); epilogue drains 8 -> 4 -> 0.
// BK=32 rows are 64 B so the fragment ds_read_b128 pattern is bank-balanced
// (8 accesses/bank = b128 throughput floor) without any swizzle.
// ---------------------------------------------------------------------------
template<int EPI>
__global__ __launch_bounds__(512, 2)
void gemm256(const u16* __restrict__ A, int lda,
             const u16* __restrict__ B, int ldb,
             const float* __restrict__ bias,
             void* __restrict__ Cv, int ldc, int K,
             const float* __restrict__ P, int nbs) {
  __shared__ u16 As[4][8192];
  __shared__ u16 Bs[4][8192];
  // chunked XCD swizzle: XCD x gets a contiguous g-range; same-m n-blocks
  // run concurrently on one XCD -> A-stripe L2 reuse. grid % 8 == 0 always.
  int nwg = gridDim.x;
  int bid = blockIdx.x;
  int chunk = nwg >> 3;
  int g = (bid & 7) * chunk + (bid >> 3);
  int nb = g & ((1 << nbs) - 1), mb = g >> nbs;
  int m0 = mb * 256, n0 = nb * 256;
  int t = threadIdx.x;
  int lane = t & 63, w = t >> 6;
  int wr = w >> 2, wc = w & 3;
  int l15 = lane & 15, quad = lane >> 4;
  int wb = w * 512;                 // wave-uniform LDS staging base (elems)
  int srow = t >> 2, sch = (t & 3) * 8;
  const u16* gA0 = A + (size_t)(m0 + srow) * lda + sch;
  const u16* gA1 = gA0 + (size_t)128 * lda;
  const u16* gB0 = B + (size_t)(n0 + srow) * ldb + sch;
  const u16* gB1 = gB0 + (size_t)128 * ldb;

  floatx4 acc[8][4];
#pragma unroll
  for (int i = 0; i < 8; ++i)
#pragma unroll
    for (int j = 0; j < 4; ++j) acc[i][j] = (floatx4){0.f, 0.f, 0.f, 0.f};

  int aoff = (wr * 128 + l15) * 32 + quad * 8;
  int boff = (wc * 64 + l15) * 32 + quad * 8;
  int KT = K >> 5;

#define STA256(ts) { int _b = (ts) & 3; int _ko = (ts) * 32;               \
    gll16(gA0 + _ko, (void*)&As[_b][wb]);                                  \
    gll16(gA1 + _ko, (void*)&As[_b][wb + 4096]); }
#define STB256(ts) { int _b = (ts) & 3; int _ko = (ts) * 32;               \
    gll16(gB0 + _ko, (void*)&Bs[_b][wb]);                                  \
    gll16(gB1 + _ko, (void*)&Bs[_b][wb + 4096]); }

  // prologue: tiles 0,1,2 in flight (12 vmem instrs / wave)
  STA256(0) STB256(0)
  STA256(1) STB256(1)
  STA256(2) STB256(2)
  asm volatile("s_waitcnt vmcnt(8)" ::: "memory");   // tile 0 landed
  asm volatile("s_barrier" ::: "memory");

  short8 af[8], bfv[4];
  for (int tt = 0; tt < KT; ++tt) {
    int bo = tt & 3;
    // ---- phase 0: issue 8 ds_reads + A-half prefetch, then 16 MFMA ----
#pragma unroll
    for (int i = 0; i < 4; ++i)
      af[i] = *(const short8*)&As[bo][aoff + i * 512];
#pragma unroll
    for (int j = 0; j < 4; ++j)
      bfv[j] = *(const short8*)&Bs[bo][boff + j * 512];
    if (tt < KT - 3) STA256(tt + 3)
    asm volatile("s_barrier" ::: "memory");
    asm volatile("s_waitcnt lgkmcnt(0)" ::: "memory");
    __builtin_amdgcn_sched_barrier(0);
    __builtin_amdgcn_s_setprio(1);
#pragma unroll
    for (int i = 0; i < 4; ++i)
#pragma unroll
      for (int j = 0; j < 4; ++j)
        acc[i][j] = __builtin_amdgcn_mfma_f32_16x16x32_bf16(af[i], bfv[j], acc[i][j], 0, 0, 0);
    __builtin_amdgcn_s_setprio(0);
    __builtin_amdgcn_sched_barrier(0);
    asm volatile("s_barrier" ::: "memory");
    // ---- phase 1: issue 4 ds_reads + B-half prefetch, then 16 MFMA ----
#pragma unroll
    for (int i = 4; i < 8; ++i)
      af[i] = *(const short8*)&As[bo][aoff + i * 512];
    if (tt < KT - 3) STB256(tt + 3)
    asm volatile("s_barrier" ::: "memory");
    asm volatile("s_waitcnt lgkmcnt(0)" ::: "memory");
    __builtin_amdgcn_sched_barrier(0);
    __builtin_amdgcn_s_setprio(1);
#pragma unroll
    for (int i = 4; i < 8; ++i)
#pragma unroll
      for (int j = 0; j < 4; ++j)
        acc[i][j] = __builtin_amdgcn_mfma_f32_16x16x32_bf16(af[i], bfv[j], acc[i][j], 0, 0, 0);
    __builtin_amdgcn_s_setprio(0);
    __builtin_amdgcn_sched_barrier(0);
    // end-of-tile wait: next tile's loads must be landed before anyone
    // crosses the trailing barrier. Counted (8), never 0 in main loop.
    if (tt < KT - 3)       { asm volatile("s_waitcnt vmcnt(8)" ::: "memory"); }
    else if (tt == KT - 3) { asm volatile("s_waitcnt vmcnt(4)" ::: "memory"); }
    else if (tt == KT - 2) { asm volatile("s_waitcnt vmcnt(0)" ::: "memory"); }
    if (tt < KT - 1) asm volatile("s_barrier" ::: "memory");
  }
#undef STA256
#undef STB256

  // epilogue: C/D layout col = lane&15, row = quad*4 + reg  [m89-verified]
#pragma unroll
  for (int i = 0; i < 8; ++i) {
    int mrow = m0 + wr * 128 + i * 16 + quad * 4;
#pragma unroll
    for (int j = 0; j < 4; ++j) {
      int col = n0 + wc * 64 + j * 16 + l15;
      float bv = bias[col];
      floatx4 a = acc[i][j];
      if (EPI == 1) {
        int bb = mrow >> 11, ti = mrow & 2047;
        float4 o; o.x = a[0] + bv; o.y = a[1] + bv; o.z = a[2] + bv; o.w = a[3] + bv;
        *(float4*)&((float*)Cv)[((size_t)bb * ldc + col) * 2048 + ti] = o;
      } else if (EPI == 2) {
        int np0 = mrow >> 1;
        int h = col >> 7;   // head from output column (128-wide head slices)
        float4 P0 = *(const float4*)&P[((size_t)np0 * 4 + h) * 4];
        float4 P1 = *(const float4*)&P[((size_t)(np0 + 1) * 4 + h) * 4];
        float a0 = a[0] + bv, a1 = a[1] + bv, a2 = a[2] + bv, a3 = a[3] + bv;
        u16* C = (u16*)Cv;
        C[(size_t)(mrow + 0) * ldc + col] = f2bf(P0.x * a0 + P0.y * a1);
        C[(size_t)(mrow + 1) * ldc + col] = f2bf(P0.z * a0 + P0.w * a1);
        C[(size_t)(mrow + 2) * ldc + col] = f2bf(P1.x * a2 + P1.y * a3);
        C[(size_t)(mrow + 3) * ldc + col] = f2bf(P1.z * a2 + P1.w * a3);
      } else {
        u16* C = (u16*)Cv;
#pragma unroll
        for (int r = 0; r < 4; ++r)
          C[(size_t)(mrow + r) * ldc + col] = f2bf(a[r] + bv);
      }
    }
  }
}

// ---------------------------------------------------------------------------
// score_kernel: thread per (n,h); QK row 2n/2n+1, q at col h*128, k at 512+h*128.
// ---------------------------------------------------------------------------
__global__ __launch_bounds__(256)
void score_kernel(const u16* __restrict__ QK, float* __restrict__ P,
                  float* __restrict__ asum) {
  int g = blockIdx.x * 256 + threadIdx.x;
  int n = g >> 2, h = g & 3;
  const u16* q0 = QK + (size_t)(2 * n) * 1024 + h * 128;
  const u16* q1 = q0 + 1024;
  const u16* k0 = q0 + 512;
  const u16* k1 = k0 + 1024;

  float s00 = 0.f, s01 = 0.f, s10 = 0.f, s11 = 0.f;
#pragma unroll
  for (int c = 0; c < 128; c += 8) {
    float fq0[8], fq1[8], fk0[8], fk1[8];
    unpack8(*(const uint4*)(q0 + c), fq0);
    unpack8(*(const uint4*)(q1 + c), fq1);
    unpack8(*(const uint4*)(k0 + c), fk0);
    unpack8(*(const uint4*)(k1 + c), fk1);
#pragma unroll
    for (int u = 0; u < 8; ++u) {
      s00 += fq0[u] * fk0[u]; s01 += fq0[u] * fk1[u];
      s10 += fq1[u] * fk0[u]; s11 += fq1[u] * fk1[u];
    }
  }
  const float sc = 0.08838834764831845f;  // 1/sqrt(128)
  s00 *= sc; s01 *= sc; s10 *= sc; s11 *= sc;
  float m0v = fmaxf(s00, s01), m1v = fmaxf(s10, s11);
  float e00 = __expf(s00 - m0v), e01 = __expf(s01 - m0v);
  float e10 = __expf(s10 - m1v), e11 = __expf(s11 - m1v);
  float i0 = 1.f / (e00 + e01), i1 = 1.f / (e10 + e11);
  float4 p; p.x = e00 * i0; p.y = e01 * i0; p.z = e10 * i1; p.w = e11 * i1;
  *(float4*)&P[(size_t)g * 4] = p;

  float pv[4] = {p.x, p.y, p.z, p.w};
#pragma unroll
  for (int k2 = 0; k2 < 4; ++k2) {
    float v = pv[k2];
    v += __shfl_down(v, 32, 64); v += __shfl_down(v, 16, 64);
    v += __shfl_down(v, 8, 64);  v += __shfl_down(v, 4, 64);
    v += __shfl_down(v, 2, 64);  v += __shfl_down(v, 1, 64);
    pv[k2] = v;
  }
  __shared__ float red[4][4];
  int lane = threadIdx.x & 63, wv = threadIdx.x >> 6;
  if (lane == 0) { red[wv][0] = pv[0]; red[wv][1] = pv[1]; red[wv][2] = pv[2]; red[wv][3] = pv[3]; }
  __syncthreads();
  if (threadIdx.x < 4) {
    float s = red[0][threadIdx.x] + red[1][threadIdx.x] + red[2][threadIdx.x] + red[3][threadIdx.x];
    int b = (blockIdx.x * 64) >> 11;
    atomicAdd(&asum[b * 4 + threadIdx.x], s);
  }
}

__global__ void avg_kernel(const float* __restrict__ asum, float* __restrict__ out) {
  int i = threadIdx.x;  // 64 = 16 b * 4
  out[16777216 + i] = asum[i] * (1.0f / 8192.0f);  // / (H=4 * T=2048)
}

// ---------------------------------------------------------------------------
// Workspace layout unchanged (~206 MiB). xe staged in d_out.
// ---------------------------------------------------------------------------
extern "C" void kernel_launch(void* const* d_in, const int* in_sizes, int n_in,
                              void* d_out, int out_size, void* d_ws, size_t ws_size,
                              hipStream_t stream) {
  const float* x    = (const float*)d_in[0];
  const float* emb  = (const float*)d_in[1];
  const float* inw  = (const float*)d_in[2];
  const float* inb  = (const float*)d_in[3];
  const float* outw = (const float*)d_in[4];
  const float* outb = (const float*)d_in[5];
  const float* phw  = (const float*)d_in[6];
  const float* phb  = (const float*)d_in[7];
  const float* imw  = (const float*)d_in[8];
  const float* imb  = (const float*)d_in[9];
  const float* ow   = (const float*)d_in[10];
  const float* ob   = (const float*)d_in[11];
  float* outF = (float*)d_out;

  char* wsb = (char*)d_ws;
  u16*   ctx    = (u16*)wsb;
  u16*   QK     = (u16*)(wsb + 67108864);
  u16*   outwT  = (u16*)(wsb + 67108864);
  u16*   phw_bf = (u16*)(wsb + 67633152);
  u16*   imw_bf = (u16*)(wsb + 68157440);
  u16*   ow_bf  = (u16*)(wsb + 68681728);
  u16*   T1T    = (u16*)(wsb + 69730304);
  u16*   T2T    = (u16*)(wsb + 70254592);
  u16*   inw_bf = (u16*)(wsb + 201326592);
  u16*   Wcomb  = (u16*)(wsb + 202899456);
  float* uv     = (float*)(wsb + 203948032);
  float* bcomb  = (float*)(wsb + 203952128);
  float* P      = (float*)(wsb + 203954176);
  float* asum   = (float*)(wsb + 206051328);
  float* zbias  = (float*)(wsb + 206051584);
  u16*   xe     = (u16*)d_out;

  // zero asum (256 B) + zbias (2 KiB) in one memset
  hipMemsetAsync(asum, 0, 2304, stream);

  // xe = transpose(x) + emb  (bf16, staged in d_out) -- biggest prep, first
  build_xe<<<8192, 256, 0, stream>>>(x, emb, xe);

  // weight conversions (one launch), then MFMA weight-fold chain
  prep_convert<<<dim3(768, 5), 256, 0, stream>>>(inw, phw, imw, ow, outw,
                                                 inw_bf, phw_bf, imw_bf, ow_bf, outwT);
  // T1T = outwT @ phw^T ; T2T = outwT @ imw^T   (512x512x512, legacy kernel)
  gemm_bt<0><<<dim3(4, 4), 256, 0, stream>>>(outwT, 512, phw_bf, 512, zbias, T1T, 512, 512, nullptr);
  gemm_bt<0><<<dim3(4, 4), 256, 0, stream>>>(outwT, 512, imw_bf, 512, zbias, T2T, 512, 512, nullptr);
  // Wcomb[:, :512] = ow_L @ T1 ; Wcomb[:, 512:] = ow_R @ T2
  gemm_bt<0><<<dim3(4, 4), 256, 0, stream>>>(ow_bf, 1024, T1T, 512, zbias, Wcomb, 1024, 512, nullptr);
  gemm_bt<0><<<dim3(4, 4), 256, 0, stream>>>(ow_bf + 512, 1024, T2T, 512, zbias, Wcomb + 512, 1024, 512, nullptr);
  // combined bias (fp32 path, tiny)
  uv_kernel<<<4, 256, 0, stream>>>(phw, phb, imw, imb, outb, uv);
  bcomb_kernel<<<2, 256, 0, stream>>>(ow, ob, uv, bcomb);

  // QK = xe @ [Wq;Wk]^T + [bq;bk]   (65536 x 1024 x 512)  -- 256^2 phased
  gemm256<0><<<1024, 512, 0, stream>>>(xe, 512, inw_bf, 512, inb,
                                       QK, 1024, 512, nullptr, 2);
  // 2x2 softmax -> P, asum
  score_kernel<<<512, 256, 0, stream>>>(QK, P, asum);
  // V GEMM + P-mix epilogue -> ctx   (65536 x 512 x 512)
  gemm256<2><<<512, 512, 0, stream>>>(xe, 512, inw_bf + 524288, 512,
                                      inb + 1024, ctx, 512, 512, P, 1);
  // folded tail: out = ctx(pairs, K=1024) @ Wcomb^T + bcomb, transposed (B,C,T)
  gemm256<1><<<256, 512, 0, stream>>>(ctx, 1024, Wcomb, 1024,
                                      bcomb, outF, 512, 1024, nullptr, 1);
  avg_kernel<<<1, 64, 0, stream>>>(asum, outF);
}

// Round 4
// 534.349 us; speedup vs baseline: 1.2261x; 1.1575x over previous
//
#include <hip/hip_runtime.h>
#include <stdint.h>

typedef unsigned short u16;
typedef short short8 __attribute__((ext_vector_type(8)));
typedef float floatx4 __attribute__((ext_vector_type(4)));

__device__ __forceinline__ u16 f2bf(float f) {
  union { float f; unsigned u; } t; t.f = f;
  return (u16)((t.u + 0x7fffu + ((t.u >> 16) & 1u)) >> 16);
}
__device__ __forceinline__ float lo16(unsigned w) { union { unsigned u; float f; } t; t.u = w << 16; return t.f; }
__device__ __forceinline__ float hi16(unsigned w) { union { unsigned u; float f; } t; t.u = w & 0xffff0000u; return t.f; }
__device__ __forceinline__ void unpack8(uint4 v, float* f) {
  f[0]=lo16(v.x); f[1]=hi16(v.x); f[2]=lo16(v.y); f[3]=hi16(v.y);
  f[4]=lo16(v.z); f[5]=hi16(v.z); f[6]=lo16(v.w); f[7]=hi16(v.w);
}
__device__ __forceinline__ uint4 pack8(const u16* o) {
  uint4 v;
  v.x = (unsigned)o[0] | ((unsigned)o[1] << 16);
  v.y = (unsigned)o[2] | ((unsigned)o[3] << 16);
  v.z = (unsigned)o[4] | ((unsigned)o[5] << 16);
  v.w = (unsigned)o[6] | ((unsigned)o[7] << 16);
  return v;
}

// async global->LDS, 16B per lane; lds dst is wave-uniform base + lane*16
__device__ __forceinline__ void gll16(const void* g, void* l) {
  __builtin_amdgcn_global_load_lds(
      (const __attribute__((address_space(1))) void*)(uintptr_t)(g),
      (__attribute__((address_space(3))) void*)(unsigned)(uintptr_t)(l),
      16, 0, 0);
}

// ---------------------------------------------------------------------------
// prep_convert: one launch for all weight conversions.
// ---------------------------------------------------------------------------
__device__ __forceinline__ void cvt4(const float* s, u16* d, int g) {
  float4 v = *(const float4*)(s + (size_t)g * 4);
  ushort4 o; o.x = f2bf(v.x); o.y = f2bf(v.y); o.z = f2bf(v.z); o.w = f2bf(v.w);
  *(ushort4*)(d + (size_t)g * 4) = o;
}
__global__ __launch_bounds__(256)
void prep_convert(const float* __restrict__ inw, const float* __restrict__ phw,
                  const float* __restrict__ imw, const float* __restrict__ ow,
                  const float* __restrict__ outw,
                  u16* __restrict__ inw_bf, u16* __restrict__ phw_bf,
                  u16* __restrict__ imw_bf, u16* __restrict__ ow_bf,
                  u16* __restrict__ outwT) {
  int which = blockIdx.y;
  int g = blockIdx.x * 256 + threadIdx.x;
  if (which == 0) { if (g < 196608) cvt4(inw, inw_bf, g); }
  else if (which == 1) { if (g < 65536) cvt4(phw, phw_bf, g); }
  else if (which == 2) { if (g < 65536) cvt4(imw, imw_bf, g); }
  else if (which == 3) { if (g < 131072) cvt4(ow, ow_bf, g); }
  else {
    if (g < 65536) {
      int i0 = (g >> 9) * 4, j = g & 511;
      ushort4 o;
      o.x = f2bf(outw[(size_t)(i0 + 0) * 512 + j]);
      o.y = f2bf(outw[(size_t)(i0 + 1) * 512 + j]);
      o.z = f2bf(outw[(size_t)(i0 + 2) * 512 + j]);
      o.w = f2bf(outw[(size_t)(i0 + 3) * 512 + j]);
      outwT[(size_t)j * 512 + i0 + 0] = o.x;
      outwT[(size_t)j * 512 + i0 + 1] = o.y;
      outwT[(size_t)j * 512 + i0 + 2] = o.z;
      outwT[(size_t)j * 512 + i0 + 3] = o.w;
    }
  }
}

// wave-per-output reductions (coalesced lane-strided reads, shuffle reduce)
__device__ __forceinline__ float wave_red(float s) {
  s += __shfl_down(s, 32, 64); s += __shfl_down(s, 16, 64);
  s += __shfl_down(s, 8, 64);  s += __shfl_down(s, 4, 64);
  s += __shfl_down(s, 2, 64);  s += __shfl_down(s, 1, 64);
  return s;
}
__global__ __launch_bounds__(256)
void uv_kernel(const float* __restrict__ phw, const float* __restrict__ phb,
               const float* __restrict__ imw, const float* __restrict__ imb,
               const float* __restrict__ outb, float* __restrict__ uv) {
  int o = blockIdx.x * 4 + (threadIdx.x >> 6);   // 0..1023, wave-per-output
  int lane = threadIdx.x & 63;
  int i = o & 511;
  const float* W = (o < 512) ? phw : imw;
  const float* bb = (o < 512) ? phb : imb;
  float s = 0.f;
#pragma unroll
  for (int c = 0; c < 512; c += 64) s += W[(size_t)i * 512 + c + lane] * outb[c + lane];
  s = wave_red(s);
  if (lane == 0) uv[o] = s + bb[i];
}

__global__ __launch_bounds__(256)
void bcomb_kernel(const float* __restrict__ ow, const float* __restrict__ ob,
                  const float* __restrict__ uv, float* __restrict__ bcomb) {
  int o = blockIdx.x * 4 + (threadIdx.x >> 6);   // 0..511, wave-per-output
  int lane = threadIdx.x & 63;
  float s = 0.f;
#pragma unroll
  for (int r = 0; r < 1024; r += 64) s += ow[(size_t)o * 1024 + r + lane] * uv[r + lane];
  s = wave_red(s);
  if (lane == 0) bcomb[o] = s + ob[o];
}

// ---------------------------------------------------------------------------
// build_xe: xe[(b*2048+t)*2+d][c] = bf16( x[b][c][d][t] + emb[d][c] )
// ---------------------------------------------------------------------------
__global__ __launch_bounds__(256)
void build_xe(const float* __restrict__ x, const float* __restrict__ emb,
              u16* __restrict__ xe) {
  __shared__ u16 tile[64][66];
  int bt = blockIdx.x;
  int tt = bt & 31, ct = (bt >> 5) & 7, d = (bt >> 8) & 1, b = bt >> 9;
  int t0 = tt * 64, c0 = ct * 64;
  int tid = threadIdx.x;
  int q = tid & 15, r = tid >> 4;
#pragma unroll
  for (int p = 0; p < 4; ++p) {
    int c = p * 16 + r;
    const float* src = x + ((size_t)((b * 512 + c0 + c) * 2 + d)) * 2048 + t0 + q * 4;
    float4 v = *(const float4*)src;
    float e = emb[d * 512 + c0 + c];
    ushort4 o; o.x = f2bf(v.x + e); o.y = f2bf(v.y + e); o.z = f2bf(v.z + e); o.w = f2bf(v.w + e);
    *(ushort4*)&tile[c][q * 4] = o;
  }
  __syncthreads();
  int cq = tid & 7, tp = tid >> 3;
  int cc0 = cq * 8;
  u16 o0[8], o1[8];
#pragma unroll
  for (int i = 0; i < 8; ++i) {
    unsigned w2 = *(const unsigned*)&tile[cc0 + i][2 * tp];
    o0[i] = (u16)(w2 & 0xffffu); o1[i] = (u16)(w2 >> 16);
  }
  size_t n = (size_t)b * 2048 + t0 + 2 * tp;
  *(uint4*)(xe + (n * 2 + d) * 512 + c0 + cc0) = pack8(o0);
  *(uint4*)(xe + ((n + 1) * 2 + d) * 512 + c0 + cc0) = pack8(o1);
}

// ---------------------------------------------------------------------------
// gemm_bt (legacy 128x128) -- only for the tiny 512^3 weight-fold GEMMs,
// batched 2-at-a-time via blockIdx.z pointer select.
// ---------------------------------------------------------------------------
__global__ __launch_bounds__(256, 3)
void gemm_bt(const u16* __restrict__ A, const u16* __restrict__ Az, int lda,
             const u16* __restrict__ B, const u16* __restrict__ Bz, int ldb,
             const float* __restrict__ bias,
             u16* __restrict__ Cv, u16* __restrict__ Cvz, int ldc, int K) {
  if (blockIdx.z) { A = Az; B = Bz; Cv = Cvz; }
  __shared__ u16 As[128 * 64];
  __shared__ u16 Bs[128 * 64];
  int m0 = blockIdx.x * 128;
  int n0 = blockIdx.y * 128;
  int t = threadIdx.x;
  int lane = t & 63;
  int w = t >> 6;
  int wm = (w >> 1) * 64, wn = (w & 1) * 64;
  int l15 = lane & 15, quad = lane >> 4;

  floatx4 acc[4][4];
#pragma unroll
  for (int i = 0; i < 4; ++i)
#pragma unroll
    for (int j = 0; j < 4; ++j) acc[i][j] = (floatx4){0.f, 0.f, 0.f, 0.f};

  int lrow = lane >> 3, lcol = (lane & 7) * 8;
  const u16* gA = A + (size_t)(m0 + w * 32 + lrow) * lda + lcol;
  const u16* gB = B + (size_t)(n0 + w * 32 + lrow) * ldb + lcol;
  u16* lA = As + (w * 32) * 64;
  u16* lB = Bs + (w * 32) * 64;

  int KT = K >> 6;
  for (int kt = 0; kt < KT; ++kt) {
    int ko = kt * 64;
#pragma unroll
    for (int j = 0; j < 4; ++j) {
      gll16(gA + (size_t)(j * 8) * lda + ko, lA + (j * 8) * 64);
      gll16(gB + (size_t)(j * 8) * ldb + ko, lB + (j * 8) * 64);
    }
    __syncthreads();
#pragma unroll
    for (int ki = 0; ki < 2; ++ki) {
      short8 af[4], bfv[4];
#pragma unroll
      for (int i = 0; i < 4; ++i)
        af[i] = *(const short8*)&As[(wm + i * 16 + l15) * 64 + ki * 32 + quad * 8];
#pragma unroll
      for (int j = 0; j < 4; ++j)
        bfv[j] = *(const short8*)&Bs[(wn + j * 16 + l15) * 64 + ki * 32 + quad * 8];
#pragma unroll
      for (int i = 0; i < 4; ++i)
#pragma unroll
        for (int j = 0; j < 4; ++j)
          acc[i][j] = __builtin_amdgcn_mfma_f32_16x16x32_bf16(af[i], bfv[j], acc[i][j], 0, 0, 0);
    }
    __syncthreads();
  }

#pragma unroll
  for (int i = 0; i < 4; ++i) {
    int mrow = m0 + wm + i * 16 + quad * 4;
#pragma unroll
    for (int j = 0; j < 4; ++j) {
      int col = n0 + wn + j * 16 + l15;
      float bv = bias[col];
      floatx4 a = acc[i][j];
#pragma unroll
      for (int r = 0; r < 4; ++r)
        Cv[(size_t)(mrow + r) * ldc + col] = f2bf(a[r] + bv);
    }
  }
}

// ---------------------------------------------------------------------------
// gemm256: 256x256 tile, 8 waves (2M x 4N), BK=32, 4-deep LDS ring buffer.
// r1-proven schedule: per tile { stage tile tt+3; s_waitcnt vmcnt(12);
// s_barrier; 12 ds_read_b128 + 32 MFMA (compiler-scheduled lgkm waits,
// setprio around MFMAs); s_barrier }. Counted vmcnt never 0 in main loop;
// epilogue drains 12 -> 8 -> 4 -> 0. LDS 128 KiB, 1 block/CU.
// BK=32 rows are 64 B -> fragment ds_read_b128 at bank-floor (8/bank).
// ---------------------------------------------------------------------------
__device__ __forceinline__ void compute_tile(const u16 (&Asr)[4][8192],
                                             const u16 (&Bsr)[4][8192],
                                             int bo, int aoff, int boff,
                                             floatx4 (&acc)[8][4]) {
  short8 af[8], bfv[4];
#pragma unroll
  for (int i = 0; i < 8; ++i)
    af[i] = *(const short8*)&Asr[bo][aoff + i * 512];
#pragma unroll
  for (int j = 0; j < 4; ++j)
    bfv[j] = *(const short8*)&Bsr[bo][boff + j * 512];
  __builtin_amdgcn_s_setprio(1);
#pragma unroll
  for (int i = 0; i < 8; ++i)
#pragma unroll
    for (int j = 0; j < 4; ++j)
      acc[i][j] = __builtin_amdgcn_mfma_f32_16x16x32_bf16(af[i], bfv[j], acc[i][j], 0, 0, 0);
  __builtin_amdgcn_s_setprio(0);
}

template<int EPI>
__global__ __launch_bounds__(512, 2)
void gemm256(const u16* __restrict__ A, int lda,
             const u16* __restrict__ B, int ldb,
             const float* __restrict__ bias,
             void* __restrict__ Cv, int ldc, int K,
             const float* __restrict__ P, int nbs) {
  __shared__ u16 As[4][8192];
  __shared__ u16 Bs[4][8192];
  // chunked XCD swizzle: XCD x gets a contiguous g-range; same-m n-blocks
  // run concurrently on one XCD -> A-stripe L2 reuse. grid % 8 == 0 always.
  int nwg = gridDim.x;
  int bid = blockIdx.x;
  int chunk = nwg >> 3;
  int g = (bid & 7) * chunk + (bid >> 3);
  int nb = g & ((1 << nbs) - 1), mb = g >> nbs;
  int m0 = mb * 256, n0 = nb * 256;
  int t = threadIdx.x;
  int lane = t & 63, w = t >> 6;
  int wr = w >> 2, wc = w & 3;
  int l15 = lane & 15, quad = lane >> 4;
  int wb = w * 512;                 // wave-uniform LDS staging base (elems)
  int srow = t >> 2, sch = (t & 3) * 8;
  const u16* gA0 = A + (size_t)(m0 + srow) * lda + sch;
  const u16* gA1 = gA0 + (size_t)128 * lda;
  const u16* gB0 = B + (size_t)(n0 + srow) * ldb + sch;
  const u16* gB1 = gB0 + (size_t)128 * ldb;

  floatx4 acc[8][4];
#pragma unroll
  for (int i = 0; i < 8; ++i)
#pragma unroll
    for (int j = 0; j < 4; ++j) acc[i][j] = (floatx4){0.f, 0.f, 0.f, 0.f};

  int aoff = (wr * 128 + l15) * 32 + quad * 8;
  int boff = (wc * 64 + l15) * 32 + quad * 8;
  int KT = K >> 5;

#define STAGE256(ts) { int _b = (ts) & 3; int _ko = (ts) * 32;             \
    gll16(gA0 + _ko, (void*)&As[_b][wb]);                                  \
    gll16(gA1 + _ko, (void*)&As[_b][wb + 4096]);                           \
    gll16(gB0 + _ko, (void*)&Bs[_b][wb]);                                  \
    gll16(gB1 + _ko, (void*)&Bs[_b][wb + 4096]); }

  STAGE256(0)
  STAGE256(1)
  STAGE256(2)
  for (int tt = 0; tt < KT - 3; ++tt) {
    STAGE256(tt + 3)
    asm volatile("s_waitcnt vmcnt(12)" ::: "memory");
    asm volatile("s_barrier" ::: "memory");
    compute_tile(As, Bs, tt & 3, aoff, boff, acc);
    asm volatile("s_barrier" ::: "memory");
  }
  asm volatile("s_waitcnt vmcnt(8)" ::: "memory");
  asm volatile("s_barrier" ::: "memory");
  compute_tile(As, Bs, (KT - 3) & 3, aoff, boff, acc);
  asm volatile("s_waitcnt vmcnt(4)" ::: "memory");
  asm volatile("s_barrier" ::: "memory");
  compute_tile(As, Bs, (KT - 2) & 3, aoff, boff, acc);
  asm volatile("s_waitcnt vmcnt(0)" ::: "memory");
  asm volatile("s_barrier" ::: "memory");
  compute_tile(As, Bs, (KT - 1) & 3, aoff, boff, acc);
#undef STAGE256

  // epilogue: C/D layout col = lane&15, row = quad*4 + reg  [m89-verified]
#pragma unroll
  for (int i = 0; i < 8; ++i) {
    int mrow = m0 + wr * 128 + i * 16 + quad * 4;
#pragma unroll
    for (int j = 0; j < 4; ++j) {
      int col = n0 + wc * 64 + j * 16 + l15;
      float bv = bias[col];
      floatx4 a = acc[i][j];
      if (EPI == 1) {
        int bb = mrow >> 11, ti = mrow & 2047;
        float4 o; o.x = a[0] + bv; o.y = a[1] + bv; o.z = a[2] + bv; o.w = a[3] + bv;
        *(float4*)&((float*)Cv)[((size_t)bb * ldc + col) * 2048 + ti] = o;
      } else if (EPI == 2) {
        int np0 = mrow >> 1;
        int h = col >> 7;   // head from output column (128-wide head slices)
        float4 P0 = *(const float4*)&P[((size_t)np0 * 4 + h) * 4];
        float4 P1 = *(const float4*)&P[((size_t)(np0 + 1) * 4 + h) * 4];
        float a0 = a[0] + bv, a1 = a[1] + bv, a2 = a[2] + bv, a3 = a[3] + bv;
        u16* C = (u16*)Cv;
        C[(size_t)(mrow + 0) * ldc + col] = f2bf(P0.x * a0 + P0.y * a1);
        C[(size_t)(mrow + 1) * ldc + col] = f2bf(P0.z * a0 + P0.w * a1);
        C[(size_t)(mrow + 2) * ldc + col] = f2bf(P1.x * a2 + P1.y * a3);
        C[(size_t)(mrow + 3) * ldc + col] = f2bf(P1.z * a2 + P1.w * a3);
      } else {
        u16* C = (u16*)Cv;
#pragma unroll
        for (int r = 0; r < 4; ++r)
          C[(size_t)(mrow + r) * ldc + col] = f2bf(a[r] + bv);
      }
    }
  }
}

// ---------------------------------------------------------------------------
// score_kernel: thread per (n,h); QK row 2n/2n+1, q at col h*128, k at 512+h*128.
// ---------------------------------------------------------------------------
__global__ __launch_bounds__(256)
void score_kernel(const u16* __restrict__ QK, float* __restrict__ P,
                  float* __restrict__ asum) {
  int g = blockIdx.x * 256 + threadIdx.x;
  int n = g >> 2, h = g & 3;
  const u16* q0 = QK + (size_t)(2 * n) * 1024 + h * 128;
  const u16* q1 = q0 + 1024;
  const u16* k0 = q0 + 512;
  const u16* k1 = k0 + 1024;

  float s00 = 0.f, s01 = 0.f, s10 = 0.f, s11 = 0.f;
#pragma unroll
  for (int c = 0; c < 128; c += 8) {
    float fq0[8], fq1[8], fk0[8], fk1[8];
    unpack8(*(const uint4*)(q0 + c), fq0);
    unpack8(*(const uint4*)(q1 + c), fq1);
    unpack8(*(const uint4*)(k0 + c), fk0);
    unpack8(*(const uint4*)(k1 + c), fk1);
#pragma unroll
    for (int u = 0; u < 8; ++u) {
      s00 += fq0[u] * fk0[u]; s01 += fq0[u] * fk1[u];
      s10 += fq1[u] * fk0[u]; s11 += fq1[u] * fk1[u];
    }
  }
  const float sc = 0.08838834764831845f;  // 1/sqrt(128)
  s00 *= sc; s01 *= sc; s10 *= sc; s11 *= sc;
  float m0v = fmaxf(s00, s01), m1v = fmaxf(s10, s11);
  float e00 = __expf(s00 - m0v), e01 = __expf(s01 - m0v);
  float e10 = __expf(s10 - m1v), e11 = __expf(s11 - m1v);
  float i0 = 1.f / (e00 + e01), i1 = 1.f / (e10 + e11);
  float4 p; p.x = e00 * i0; p.y = e01 * i0; p.z = e10 * i1; p.w = e11 * i1;
  *(float4*)&P[(size_t)g * 4] = p;

  float pv[4] = {p.x, p.y, p.z, p.w};
#pragma unroll
  for (int k2 = 0; k2 < 4; ++k2) {
    float v = pv[k2];
    v += __shfl_down(v, 32, 64); v += __shfl_down(v, 16, 64);
    v += __shfl_down(v, 8, 64);  v += __shfl_down(v, 4, 64);
    v += __shfl_down(v, 2, 64);  v += __shfl_down(v, 1, 64);
    pv[k2] = v;
  }
  __shared__ float red[4][4];
  int lane = threadIdx.x & 63, wv = threadIdx.x >> 6;
  if (lane == 0) { red[wv][0] = pv[0]; red[wv][1] = pv[1]; red[wv][2] = pv[2]; red[wv][3] = pv[3]; }
  __syncthreads();
  if (threadIdx.x < 4) {
    float s = red[0][threadIdx.x] + red[1][threadIdx.x] + red[2][threadIdx.x] + red[3][threadIdx.x];
    int b = (blockIdx.x * 64) >> 11;
    atomicAdd(&asum[b * 4 + threadIdx.x], s);
  }
}

__global__ void avg_kernel(const float* __restrict__ asum, float* __restrict__ out) {
  int i = threadIdx.x;  // 64 = 16 b * 4
  out[16777216 + i] = asum[i] * (1.0f / 8192.0f);  // / (H=4 * T=2048)
}

// ---------------------------------------------------------------------------
// Workspace layout unchanged (~206 MiB). xe staged in d_out.
// ---------------------------------------------------------------------------
extern "C" void kernel_launch(void* const* d_in, const int* in_sizes, int n_in,
                              void* d_out, int out_size, void* d_ws, size_t ws_size,
                              hipStream_t stream) {
  const float* x    = (const float*)d_in[0];
  const float* emb  = (const float*)d_in[1];
  const float* inw  = (const float*)d_in[2];
  const float* inb  = (const float*)d_in[3];
  const float* outw = (const float*)d_in[4];
  const float* outb = (const float*)d_in[5];
  const float* phw  = (const float*)d_in[6];
  const float* phb  = (const float*)d_in[7];
  const float* imw  = (const float*)d_in[8];
  const float* imb  = (const float*)d_in[9];
  const float* ow   = (const float*)d_in[10];
  const float* ob   = (const float*)d_in[11];
  float* outF = (float*)d_out;

  char* wsb = (char*)d_ws;
  u16*   ctx    = (u16*)wsb;
  u16*   QK     = (u16*)(wsb + 67108864);
  u16*   outwT  = (u16*)(wsb + 67108864);
  u16*   phw_bf = (u16*)(wsb + 67633152);
  u16*   imw_bf = (u16*)(wsb + 68157440);
  u16*   ow_bf  = (u16*)(wsb + 68681728);
  u16*   T1T    = (u16*)(wsb + 69730304);
  u16*   T2T    = (u16*)(wsb + 70254592);
  u16*   inw_bf = (u16*)(wsb + 201326592);
  u16*   Wcomb  = (u16*)(wsb + 202899456);
  float* uv     = (float*)(wsb + 203948032);
  float* bcomb  = (float*)(wsb + 203952128);
  float* P      = (float*)(wsb + 203954176);
  float* asum   = (float*)(wsb + 206051328);
  float* zbias  = (float*)(wsb + 206051584);
  u16*   xe     = (u16*)d_out;

  // zero asum (256 B) + zbias (2 KiB) in one memset
  hipMemsetAsync(asum, 0, 2304, stream);

  // xe = transpose(x) + emb  (bf16, staged in d_out) -- biggest prep, first
  build_xe<<<8192, 256, 0, stream>>>(x, emb, xe);

  // weight conversions (one launch), then MFMA weight-fold chain (batched x2)
  prep_convert<<<dim3(768, 5), 256, 0, stream>>>(inw, phw, imw, ow, outw,
                                                 inw_bf, phw_bf, imw_bf, ow_bf, outwT);
  // z=0: T1T = outwT @ phw^T ; z=1: T2T = outwT @ imw^T   (512x512x512)
  gemm_bt<<<dim3(4, 4, 2), 256, 0, stream>>>(outwT, outwT, 512,
                                             phw_bf, imw_bf, 512, zbias,
                                             T1T, T2T, 512, 512);
  // z=0: Wcomb[:, :512] = ow_L @ T1 ; z=1: Wcomb[:, 512:] = ow_R @ T2
  gemm_bt<<<dim3(4, 4, 2), 256, 0, stream>>>(ow_bf, ow_bf + 512, 1024,
                                             T1T, T2T, 512, zbias,
                                             Wcomb, Wcomb + 512, 1024, 512);
  // combined bias (fp32 path, wave-per-output coalesced)
  uv_kernel<<<256, 256, 0, stream>>>(phw, phb, imw, imb, outb, uv);
  bcomb_kernel<<<128, 256, 0, stream>>>(ow, ob, uv, bcomb);

  // QK = xe @ [Wq;Wk]^T + [bq;bk]   (65536 x 1024 x 512)  -- 256^2, DEPTH=4
  gemm256<0><<<1024, 512, 0, stream>>>(xe, 512, inw_bf, 512, inb,
                                       QK, 1024, 512, nullptr, 2);
  // 2x2 softmax -> P, asum
  score_kernel<<<512, 256, 0, stream>>>(QK, P, asum);
  // V GEMM + P-mix epilogue -> ctx   (65536 x 512 x 512)
  gemm256<2><<<512, 512, 0, stream>>>(xe, 512, inw_bf + 524288, 512,
                                      inb + 1024, ctx, 512, 512, P, 1);
  // folded tail: out = ctx(pairs, K=1024) @ Wcomb^T + bcomb, (B,C,T) write
  gemm256<1><<<256, 512, 0, stream>>>(ctx, 1024, Wcomb, 1024,
                                      bcomb, outF, 512, 1024, nullptr, 1);
  avg_kernel<<<1, 64, 0, stream>>>(asum, outF);
}